// Round 1
// baseline (288.188 us; speedup 1.0000x reference)
//
#include <hip/hip_runtime.h>

#define G 256
#define GP1 257          // G + phantom group
#define NPAIRS 32896.0f  // 257*256/2

// ---------------------------------------------------------------------------
// Kernel 0: zero the 3*G float accumulators in workspace (cnt, sum, sumsq).
// Harness poisons d_ws once and never re-poisons between replays, so we must
// re-init every call.
// ---------------------------------------------------------------------------
__global__ void zero_ws_kernel(float* __restrict__ ws) {
    int i = blockIdx.x * blockDim.x + threadIdx.x;
    if (i < 3 * G) ws[i] = 0.0f;
}

// ---------------------------------------------------------------------------
// Kernel 1: single-pass per-group cnt / sum / sumsq.
// Per-block LDS bins (256 each), LDS float atomics, then one global
// atomicAdd per bin per block.
// ---------------------------------------------------------------------------
__global__ __launch_bounds__(256) void segstats_kernel(
        const float4* __restrict__ pred,
        const int4*   __restrict__ tgt,
        float* __restrict__ ws,   // [3*G]: cnt | sum | sumsq
        int nvec) {
    __shared__ float s_cnt[G];
    __shared__ float s_sum[G];
    __shared__ float s_sq[G];

    for (int i = threadIdx.x; i < G; i += blockDim.x) {
        s_cnt[i] = 0.0f; s_sum[i] = 0.0f; s_sq[i] = 0.0f;
    }
    __syncthreads();

    const int stride = gridDim.x * blockDim.x;
    for (int i = blockIdx.x * blockDim.x + threadIdx.x; i < nvec; i += stride) {
        float4 p = pred[i];
        int4   t = tgt[i];
        atomicAdd(&s_cnt[t.x], 1.0f);
        atomicAdd(&s_sum[t.x], p.x);
        atomicAdd(&s_sq [t.x], p.x * p.x);
        atomicAdd(&s_cnt[t.y], 1.0f);
        atomicAdd(&s_sum[t.y], p.y);
        atomicAdd(&s_sq [t.y], p.y * p.y);
        atomicAdd(&s_cnt[t.z], 1.0f);
        atomicAdd(&s_sum[t.z], p.z);
        atomicAdd(&s_sq [t.z], p.z * p.z);
        atomicAdd(&s_cnt[t.w], 1.0f);
        atomicAdd(&s_sum[t.w], p.w);
        atomicAdd(&s_sq [t.w], p.w * p.w);
    }
    __syncthreads();

    for (int i = threadIdx.x; i < G; i += blockDim.x) {
        atomicAdd(&ws[i],         s_cnt[i]);
        atomicAdd(&ws[G + i],     s_sum[i]);
        atomicAdd(&ws[2 * G + i], s_sq[i]);
    }
}

// ---------------------------------------------------------------------------
// Kernel 2: per-group mean/std + pairwise v_iou mean over 257 groups
// (group 256 is the phantom: mean=0, std=0). One block of 256 threads.
// ---------------------------------------------------------------------------
__global__ __launch_bounds__(256) void pairloss_kernel(
        const float* __restrict__ ws,
        float* __restrict__ out) {
    __shared__ float m[GP1];
    __shared__ float sd[GP1];
    __shared__ float red[256];

    const int t = threadIdx.x;
    if (t < G) {
        float cnt = ws[t];
        float s1  = ws[G + t];
        float sq  = ws[2 * G + t];
        float mean = s1 / cnt;
        float ss   = sq - s1 * s1 / cnt;              // = sum((x-mean)^2)
        float sdev = (cnt > 1.0f)
                   ? sqrtf(fmaxf(ss, 0.0f) / (cnt - 1.0f))
                   : 0.0f;
        m[t]  = mean;
        sd[t] = sdev;
    }
    if (t == 0) { m[G] = 0.0f; sd[G] = 0.0f; }
    __syncthreads();

    float acc = 0.0f;
    for (int i = 0; i < GP1; ++i) {
        float mi = m[i], si = sd[i];
        for (int j = i + 1 + t; j < GP1; j += 256) {
            float d = fabsf(m[j] - mi);
            float s = si + sd[j];
            acc += s / (d + s);
        }
    }

    red[t] = acc;
    __syncthreads();
    for (int off = 128; off > 0; off >>= 1) {
        if (t < off) red[t] += red[t + off];
        __syncthreads();
    }
    if (t == 0) out[0] = red[0] / NPAIRS;
}

// ---------------------------------------------------------------------------
extern "C" void kernel_launch(void* const* d_in, const int* in_sizes, int n_in,
                              void* d_out, int out_size, void* d_ws, size_t ws_size,
                              hipStream_t stream) {
    const float* pred = (const float*)d_in[0];
    const int*   tgt  = (const int*)d_in[1];
    float* out = (float*)d_out;
    float* ws  = (float*)d_ws;

    const int n    = in_sizes[0];       // 16,777,216 (divisible by 4)
    const int nvec = n / 4;

    zero_ws_kernel<<<4, 256, 0, stream>>>(ws);

    const int blocks = 2048;            // 8 blocks/CU, grid-stride
    segstats_kernel<<<blocks, 256, 0, stream>>>(
        (const float4*)pred, (const int4*)tgt, ws, nvec);

    pairloss_kernel<<<1, 256, 0, stream>>>(ws, out);
}

// Round 2
// 94.707 us; speedup vs baseline: 3.0429x; 3.0429x over previous
//
#include <hip/hip_runtime.h>

#define G 256
#define GP1 257          // G + phantom group
#define NPAIRS 32896.0f  // 257*256/2

typedef unsigned long long u64;

// Fixed-point scales: sum at 2^16, sumsq at 2^15.
#define S1F 65536.0f
#define S2F 32768.0f

// ---------------------------------------------------------------------------
// Kernel 0: zero the 3*G u64 accumulators (cnt | sum_fixed | sumsq_fixed).
// Harness poisons d_ws once and never re-poisons between replays.
// ---------------------------------------------------------------------------
__global__ void zero_ws_kernel(u64* __restrict__ ws) {
    int i = blockIdx.x * blockDim.x + threadIdx.x;
    if (i < 3 * G) ws[i] = 0ULL;
}

// ---------------------------------------------------------------------------
// Kernel 1: single-pass per-group cnt / sum / sumsq in fixed point.
// Native integer LDS atomics (ds_add_u32) — no FP-atomic CAS loops.
// Per-block int32 partials -> one u64 global atomic per bin per block.
// ---------------------------------------------------------------------------
__global__ __launch_bounds__(256) void segstats_kernel(
        const float4* __restrict__ pred,
        const int4*   __restrict__ tgt,
        u64* __restrict__ ws,   // [3*G]: cnt | sum | sumsq (as u64 two's-compl)
        int nvec) {
    __shared__ int s_cnt[G];
    __shared__ int s_sum[G];
    __shared__ int s_sq[G];

    for (int i = threadIdx.x; i < G; i += 256) {
        s_cnt[i] = 0; s_sum[i] = 0; s_sq[i] = 0;
    }
    __syncthreads();

    const int stride = gridDim.x * 256;
    for (int i = blockIdx.x * 256 + threadIdx.x; i < nvec; i += stride) {
        float4 p = pred[i];
        int4   t = tgt[i];

        atomicAdd(&s_cnt[t.x], 1);
        atomicAdd(&s_sum[t.x], __float2int_rn(p.x * S1F));
        atomicAdd(&s_sq [t.x], __float2int_rn(p.x * p.x * S2F));

        atomicAdd(&s_cnt[t.y], 1);
        atomicAdd(&s_sum[t.y], __float2int_rn(p.y * S1F));
        atomicAdd(&s_sq [t.y], __float2int_rn(p.y * p.y * S2F));

        atomicAdd(&s_cnt[t.z], 1);
        atomicAdd(&s_sum[t.z], __float2int_rn(p.z * S1F));
        atomicAdd(&s_sq [t.z], __float2int_rn(p.z * p.z * S2F));

        atomicAdd(&s_cnt[t.w], 1);
        atomicAdd(&s_sum[t.w], __float2int_rn(p.w * S1F));
        atomicAdd(&s_sq [t.w], __float2int_rn(p.w * p.w * S2F));
    }
    __syncthreads();

    // Widen to 64-bit (two's complement) and merge globally with native
    // u64 atomics. Signed values survive via wraparound addition.
    for (int i = threadIdx.x; i < G; i += 256) {
        atomicAdd(&ws[i],         (u64)(long long)s_cnt[i]);
        atomicAdd(&ws[G + i],     (u64)(long long)s_sum[i]);
        atomicAdd(&ws[2 * G + i], (u64)(long long)s_sq[i]);
    }
}

// ---------------------------------------------------------------------------
// Kernel 2: per-group mean/std (double, de-fixed-point) + pairwise v_iou mean
// over 257 groups (group 256 is the phantom: mean=0, std=0). One block.
// ---------------------------------------------------------------------------
__global__ __launch_bounds__(256) void pairloss_kernel(
        const u64* __restrict__ ws,
        float* __restrict__ out) {
    __shared__ float m[GP1];
    __shared__ float sd[GP1];
    __shared__ float red[256];

    const int t = threadIdx.x;
    if (t < G) {
        double cnt = (double)(long long)ws[t];
        double s1  = (double)(long long)ws[G + t]     * (1.0 / 65536.0);
        double sq  = (double)(long long)ws[2 * G + t] * (1.0 / 32768.0);
        double mean = s1 / cnt;
        double ss   = sq - s1 * s1 / cnt;             // = sum((x-mean)^2)
        double sdev = (cnt > 1.0)
                    ? sqrt(fmax(ss, 0.0) / (cnt - 1.0))
                    : 0.0;
        m[t]  = (float)mean;
        sd[t] = (float)sdev;
    }
    if (t == 0) { m[G] = 0.0f; sd[G] = 0.0f; }
    __syncthreads();

    float acc = 0.0f;
    for (int i = 0; i < GP1; ++i) {
        float mi = m[i], si = sd[i];
        for (int j = i + 1 + t; j < GP1; j += 256) {
            float d = fabsf(m[j] - mi);
            float s = si + sd[j];
            acc += s / (d + s);
        }
    }

    red[t] = acc;
    __syncthreads();
    for (int off = 128; off > 0; off >>= 1) {
        if (t < off) red[t] += red[t + off];
        __syncthreads();
    }
    if (t == 0) out[0] = red[0] / NPAIRS;
}

// ---------------------------------------------------------------------------
extern "C" void kernel_launch(void* const* d_in, const int* in_sizes, int n_in,
                              void* d_out, int out_size, void* d_ws, size_t ws_size,
                              hipStream_t stream) {
    const float* pred = (const float*)d_in[0];
    const int*   tgt  = (const int*)d_in[1];
    float* out = (float*)d_out;
    u64*   ws  = (u64*)d_ws;

    const int n    = in_sizes[0];       // 16,777,216 (divisible by 4)
    const int nvec = n / 4;

    zero_ws_kernel<<<4, 256, 0, stream>>>(ws);

    const int blocks = 2048;            // 8 blocks/CU, grid-stride
    segstats_kernel<<<blocks, 256, 0, stream>>>(
        (const float4*)pred, (const int4*)tgt, ws, nvec);

    pairloss_kernel<<<1, 256, 0, stream>>>(ws, out);
}

// Round 3
// 86.568 us; speedup vs baseline: 3.3290x; 1.0940x over previous
//
#include <hip/hip_runtime.h>

#define G 256
#define GP1 257          // G + phantom group
#define NPAIRS 32896.0f  // 257*256/2

typedef unsigned long long u64;

// Fixed-point scales: sum at 2^16, sumsq at 2^15.
#define S1F 65536.0f
#define S2F 32768.0f
// Per-element bias keeping the packed 48-bit sum field nonnegative (|x|<32).
#define BIAS (1 << 21)

// ---------------------------------------------------------------------------
// Kernel 0: zero the 3*G u64 accumulators (cnt | sum_fixed | sumsq_fixed).
// ---------------------------------------------------------------------------
__global__ void zero_ws_kernel(u64* __restrict__ ws) {
    int i = blockIdx.x * blockDim.x + threadIdx.x;
    if (i < 3 * G) ws[i] = 0ULL;
}

// ---------------------------------------------------------------------------
// Kernel 1: single-pass per-group cnt / sum / sumsq in fixed point.
//  - packed u64 LDS atomic: (cnt<<48) + (sum_fixed + BIAS)   [ds_add_u64]
//  - u32 LDS atomic for sumsq                                 [ds_add_u32]
//  - 2 replicas (even/odd wave) to cut same-address contention
//  - manual x4 unroll: 8 outstanding loads per lane before atomic burst
// ---------------------------------------------------------------------------
__global__ __launch_bounds__(256) void segstats_kernel(
        const float4* __restrict__ pred,
        const int4*   __restrict__ tgt,
        u64* __restrict__ ws,   // [3*G]: cnt | sum | sumsq (u64 two's-compl)
        int nvec) {
    __shared__ u64      s_ps[2][G];  // packed cnt|sum
    __shared__ unsigned s_sq[2][G];

    for (int i = threadIdx.x; i < 2 * G; i += 256) {
        ((u64*)s_ps)[i] = 0ULL;
        ((unsigned*)s_sq)[i] = 0u;
    }
    __syncthreads();

    const int wrep = (threadIdx.x >> 6) & 1;   // wave parity -> replica
    u64*      ps   = s_ps[wrep];
    unsigned* sq   = s_sq[wrep];

#define ACC1(px, tx)                                                          \
    do {                                                                      \
        u64 a_ = ((u64)1 << 48) +                                             \
                 (u64)(unsigned)(__float2int_rn((px) * S1F) + BIAS);          \
        atomicAdd(&ps[tx], a_);                                               \
        atomicAdd(&sq[tx], (unsigned)__float2int_rn((px) * (px) * S2F));      \
    } while (0)

#define ACC4(p_, t_)                                                          \
    do {                                                                      \
        ACC1(p_.x, t_.x); ACC1(p_.y, t_.y);                                   \
        ACC1(p_.z, t_.z); ACC1(p_.w, t_.w);                                   \
    } while (0)

    const int tid    = blockIdx.x * 256 + threadIdx.x;
    const int stride = gridDim.x * 256;

    int i = tid;
    for (; i + 3 * stride < nvec; i += 4 * stride) {
        // Batch-issue all 8 loads first (memory-level parallelism).
        float4 p0 = pred[i];
        float4 p1 = pred[i + stride];
        float4 p2 = pred[i + 2 * stride];
        float4 p3 = pred[i + 3 * stride];
        int4   t0 = tgt[i];
        int4   t1 = tgt[i + stride];
        int4   t2 = tgt[i + 2 * stride];
        int4   t3 = tgt[i + 3 * stride];
        ACC4(p0, t0); ACC4(p1, t1); ACC4(p2, t2); ACC4(p3, t3);
    }
    for (; i < nvec; i += stride) {
        float4 p = pred[i];
        int4   t = tgt[i];
        ACC4(p, t);
    }
#undef ACC4
#undef ACC1

    __syncthreads();

    // Merge replicas, unpack, flush to global with native u64 atomics.
    for (int b = threadIdx.x; b < G; b += 256) {
        u64 packed = s_ps[0][b] + s_ps[1][b];
        u64 cnt    = packed >> 48;
        long long sum_fixed =
            (long long)(packed & 0xFFFFFFFFFFFFULL) - (long long)cnt * BIAS;
        u64 sqs = (u64)(s_sq[0][b] + s_sq[1][b]);
        if (cnt) {
            atomicAdd(&ws[b],         cnt);
            atomicAdd(&ws[G + b],     (u64)sum_fixed);
            atomicAdd(&ws[2 * G + b], sqs);
        }
    }
}

// ---------------------------------------------------------------------------
// Kernel 2: per-group mean/std (double, de-fixed-point) + pairwise v_iou mean
// over 257 groups (group 256 is the phantom: mean=0, std=0). One block.
// ---------------------------------------------------------------------------
__global__ __launch_bounds__(256) void pairloss_kernel(
        const u64* __restrict__ ws,
        float* __restrict__ out) {
    __shared__ float m[GP1];
    __shared__ float sd[GP1];
    __shared__ float red[256];

    const int t = threadIdx.x;
    if (t < G) {
        double cnt = (double)(long long)ws[t];
        double s1  = (double)(long long)ws[G + t]     * (1.0 / 65536.0);
        double sq  = (double)(long long)ws[2 * G + t] * (1.0 / 32768.0);
        double mean = s1 / cnt;
        double ss   = sq - s1 * s1 / cnt;             // = sum((x-mean)^2)
        double sdev = (cnt > 1.0)
                    ? sqrt(fmax(ss, 0.0) / (cnt - 1.0))
                    : 0.0;
        m[t]  = (float)mean;
        sd[t] = (float)sdev;
    }
    if (t == 0) { m[G] = 0.0f; sd[G] = 0.0f; }
    __syncthreads();

    float acc = 0.0f;
    for (int i = 0; i < GP1; ++i) {
        float mi = m[i], si = sd[i];
        for (int j = i + 1 + t; j < GP1; j += 256) {
            float d = fabsf(m[j] - mi);
            float s = si + sd[j];
            acc += s / (d + s);
        }
    }

    red[t] = acc;
    __syncthreads();
    for (int off = 128; off > 0; off >>= 1) {
        if (t < off) red[t] += red[t + off];
        __syncthreads();
    }
    if (t == 0) out[0] = red[0] / NPAIRS;
}

// ---------------------------------------------------------------------------
extern "C" void kernel_launch(void* const* d_in, const int* in_sizes, int n_in,
                              void* d_out, int out_size, void* d_ws, size_t ws_size,
                              hipStream_t stream) {
    const float* pred = (const float*)d_in[0];
    const int*   tgt  = (const int*)d_in[1];
    float* out = (float*)d_out;
    u64*   ws  = (u64*)d_ws;

    const int n    = in_sizes[0];       // 16,777,216 (divisible by 4)
    const int nvec = n / 4;

    zero_ws_kernel<<<4, 256, 0, stream>>>(ws);

    const int blocks = 2048;            // 8 blocks/CU, grid-stride
    segstats_kernel<<<blocks, 256, 0, stream>>>(
        (const float4*)pred, (const int4*)tgt, ws, nvec);

    pairloss_kernel<<<1, 256, 0, stream>>>(ws, out);
}

// Round 4
// 66.151 us; speedup vs baseline: 4.3565x; 1.3086x over previous
//
#include <hip/hip_runtime.h>

#define G 256
#define GP1 257          // G + phantom group
#define NPAIRS 32896.0f  // 257*256/2

typedef unsigned long long u64;
typedef unsigned int u32;

// Fixed point: x scaled by 2^13, per-element bias 2^18 on the sum field.
// Packed u64 LDS accumulator: [63:51] cnt | [50:25] biased sum | [24:0] sumsq
#define XS 8192.0f
#define XBIAS 262144      // 1<<18

// ws layout (u32 indices unless noted):
//   CNT2: 64 blocks x 256 bins u32  @  16KB
//   SUM2: 64 x 256 i32              @  80KB
//   SQ2 : 64 x 256 u64              @ 144KB  (u64 index 18432)
//   ST1 : nblk x 768 u32 partials   @ 272KB  (3KB per block)
#define CNT2_OFF 4096
#define SUM2_OFF 20480
#define SQ2_OFF64 18432
#define ST1_OFF 69632
#define ST1_BYTE_OFF (272*1024)
#define NB2 64

// ---------------------------------------------------------------------------
// Kernel 1: per-block per-group stats, one packed u64 LDS atomic per element,
// one replica per wave (4). Block partial -> private ws slice, plain stores.
// ---------------------------------------------------------------------------
__global__ __launch_bounds__(256) void segstats_kernel(
        const float4* __restrict__ pred,
        const int4*   __restrict__ tgt,
        u32* __restrict__ ws,
        int nvec) {
    __shared__ u64 h[4][G];
    for (int i = threadIdx.x; i < 4 * G; i += 256) ((u64*)h)[i] = 0ULL;
    __syncthreads();

    u64* hw = h[threadIdx.x >> 6];   // per-wave replica

#define ACC1(px, tx)                                                          \
    do {                                                                      \
        u32 sf = (u32)__float2int_rn(fmaf((px), XS, (float)XBIAS));           \
        u32 qf = (u32)__float2int_rn((px) * (px) * XS);                       \
        atomicAdd(&hw[tx], ((u64)1 << 51) + ((u64)sf << 25) + (u64)qf);       \
    } while (0)

#define ACC4(p_, t_)                                                          \
    do {                                                                      \
        ACC1(p_.x, t_.x); ACC1(p_.y, t_.y);                                   \
        ACC1(p_.z, t_.z); ACC1(p_.w, t_.w);                                   \
    } while (0)

    const int stride = gridDim.x * 256;
    int i = blockIdx.x * 256 + threadIdx.x;
    for (; i + 3 * stride < nvec; i += 4 * stride) {
        float4 p0 = pred[i];
        float4 p1 = pred[i + stride];
        float4 p2 = pred[i + 2 * stride];
        float4 p3 = pred[i + 3 * stride];
        int4   t0 = tgt[i];
        int4   t1 = tgt[i + stride];
        int4   t2 = tgt[i + 2 * stride];
        int4   t3 = tgt[i + 3 * stride];
        ACC4(p0, t0); ACC4(p1, t1); ACC4(p2, t2); ACC4(p3, t3);
    }
    for (; i < nvec; i += stride) {
        float4 p = pred[i];
        int4   t = tgt[i];
        ACC4(p, t);
    }
#undef ACC4
#undef ACC1

    __syncthreads();

    // Merge 4 replicas, unpack, debias, store block-private partial.
    u32* pp = ws + ST1_OFF + blockIdx.x * 768;
    for (int b = threadIdx.x; b < G; b += 256) {
        u32 cnt = 0, sq = 0; int sum = 0;
        for (int r = 0; r < 4; ++r) {
            u64 v = h[r][b];
            cnt += (u32)(v >> 51);
            sum += (int)((v >> 25) & 0x3FFFFFFu);
            sq  += (u32)(v & 0x1FFFFFFu);
        }
        sum -= (int)cnt * XBIAS;
        pp[b]         = cnt;
        pp[G + b]     = (u32)sum;
        pp[2 * G + b] = sq;
    }
}

// ---------------------------------------------------------------------------
// Kernel 2: 64 blocks fold nblk partials -> 64 partials (coalesced reads,
// no atomics). sq widened to u64.
// ---------------------------------------------------------------------------
__global__ __launch_bounds__(256) void reduce1_kernel(u32* __restrict__ ws,
                                                      int nblk) {
    const int j = blockIdx.x, t = threadIdx.x;
    u32 c = 0; long long s = 0; u64 q = 0;
    for (int p = j; p < nblk; p += NB2) {
        const u32* pp = ws + ST1_OFF + p * 768;
        c += pp[t];
        s += (int)pp[G + t];
        q += (u64)pp[2 * G + t];
    }
    ws[CNT2_OFF + j * G + t] = c;
    ws[SUM2_OFF + j * G + t] = (u32)(int)s;
    ((u64*)ws)[SQ2_OFF64 + j * G + t] = q;
}

// ---------------------------------------------------------------------------
// Kernel 3: fold 64 partials per bin (thread t = bin t), finalize mean/std
// in double, then pairwise v_iou mean over 257 groups. One block.
// ---------------------------------------------------------------------------
__global__ __launch_bounds__(256) void pairloss_kernel(
        const u32* __restrict__ ws,
        float* __restrict__ out) {
    __shared__ float m[GP1];
    __shared__ float sd[GP1];
    __shared__ float red[256];

    const int t = threadIdx.x;
    {
        u32 c = 0; long long s = 0; u64 q = 0;
        for (int j = 0; j < NB2; ++j) {
            c += ws[CNT2_OFF + j * G + t];
            s += (int)ws[SUM2_OFF + j * G + t];
            q += ((const u64*)ws)[SQ2_OFF64 + j * G + t];
        }
        double cnt = (double)c;
        double sum = (double)s * (1.0 / 8192.0);
        double sqs = (double)(long long)q * (1.0 / 8192.0);
        double mean = sum / cnt;
        double ss   = sqs - sum * sum / cnt;
        double sdev = (cnt > 1.0) ? sqrt(fmax(ss, 0.0) / (cnt - 1.0)) : 0.0;
        m[t]  = (float)mean;
        sd[t] = (float)sdev;
    }
    if (t == 0) { m[G] = 0.0f; sd[G] = 0.0f; }
    __syncthreads();

    float acc = 0.0f;
    for (int i = 0; i < GP1; ++i) {
        float mi = m[i], si = sd[i];
        for (int j = i + 1 + t; j < GP1; j += 256) {
            float d = fabsf(m[j] - mi);
            float s = si + sd[j];
            acc += s / (d + s);
        }
    }

    red[t] = acc;
    __syncthreads();
    for (int off = 128; off > 0; off >>= 1) {
        if (t < off) red[t] += red[t + off];
        __syncthreads();
    }
    if (t == 0) out[0] = red[0] / NPAIRS;
}

// ---------------------------------------------------------------------------
extern "C" void kernel_launch(void* const* d_in, const int* in_sizes, int n_in,
                              void* d_out, int out_size, void* d_ws, size_t ws_size,
                              hipStream_t stream) {
    const float* pred = (const float*)d_in[0];
    const int*   tgt  = (const int*)d_in[1];
    float* out = (float*)d_out;
    u32*   ws  = (u32*)d_ws;

    const int n    = in_sizes[0];       // 16,777,216 (divisible by 4)
    const int nvec = n / 4;

    // Partial capacity bounded by workspace size (3KB per block).
    long long cap = ((long long)ws_size - ST1_BYTE_OFF) / 3072;
    int nblk = (int)(cap < 1 ? 1 : (cap > 1024 ? 1024 : cap));

    segstats_kernel<<<nblk, 256, 0, stream>>>(
        (const float4*)pred, (const int4*)tgt, ws, nvec);

    reduce1_kernel<<<NB2, 256, 0, stream>>>(ws, nblk);

    pairloss_kernel<<<1, 256, 0, stream>>>(ws, out);
}